// Round 11
// baseline (364.634 us; speedup 1.0000x reference)
//
#include <hip/hip_runtime.h>
#include <math.h>

__device__ __forceinline__ float elu1(float z)  { return z > 0.f ? z : (__expf(z) - 1.f); }

// bf16 helpers (RTN-even)
__device__ __forceinline__ ushort f2b(float f) {
    uint u = __float_as_uint(f);
    uint r = (u + 0x7FFFu + ((u >> 16) & 1u)) >> 16;
    return (ushort)r;
}
__device__ __forceinline__ float b2f(ushort h) { return __uint_as_float(((uint)h) << 16); }
__device__ __forceinline__ float b2f_lo(uint u) { return __uint_as_float(u << 16); }
__device__ __forceinline__ float b2f_hi(uint u) { return __uint_as_float(u & 0xFFFF0000u); }

typedef __attribute__((ext_vector_type(8))) short short8b;   // 8 bf16 = 4 VGPRs (MFMA A/B frag)
typedef __attribute__((ext_vector_type(4))) float f32x4;     // MFMA C/D frag
typedef __attribute__((ext_vector_type(2))) float floatx2;   // packed fp32 (v_pk_*)

#define SCAN_BPB 1024   // elements per scan block (256 threads x 4)

// ---------------- CSR build (stores SRC node id per edge, segmented by dst) ----------------

__global__ void k_hist(const int* __restrict__ ei, int E, int Et, int* __restrict__ deg) {
    int i = blockIdx.x * blockDim.x + threadIdx.x;
    if (i < Et) {
        int d = (i < E) ? ei[E + i] : (i - E);   // self-loop edges: dst = i - E
        atomicAdd(&deg[d], 1);
    }
}

// ---- two-level scan ----

__global__ __launch_bounds__(256) void k_scan1(const int* __restrict__ deg, int N,
                                               int* __restrict__ bsum) {
    __shared__ int ts[256];
    int b = blockIdx.x, tid = threadIdx.x;
    int base = b * SCAN_BPB + tid * 4;
    int s = 0;
    if (base + 3 < N) {
        int4 v = *(const int4*)(deg + base);
        s = v.x + v.y + v.z + v.w;
    } else {
        for (int i = 0; i < 4; i++) if (base + i < N) s += deg[base + i];
    }
    ts[tid] = s;
    __syncthreads();
    for (int ofs = 128; ofs > 0; ofs >>= 1) {
        if (tid < ofs) ts[tid] += ts[tid + ofs];
        __syncthreads();
    }
    if (tid == 0) bsum[b] = ts[0];
}

__global__ __launch_bounds__(256) void k_scan2(int* __restrict__ bsum, int nb,
                                               int* __restrict__ offsets, int N) {
    __shared__ int sums[256];
    int tid = threadIdx.x;
    int v = (tid < nb) ? bsum[tid] : 0;
    sums[tid] = v;
    __syncthreads();
    for (int ofs = 1; ofs < 256; ofs <<= 1) {
        int t = 0;
        if (tid >= ofs) t = sums[tid - ofs];
        __syncthreads();
        sums[tid] += t;
        __syncthreads();
    }
    if (tid < nb) bsum[tid] = sums[tid] - v;   // exclusive
    if (tid == 255) offsets[N] = sums[255];    // grand total
}

__global__ __launch_bounds__(256) void k_scan3(const int* __restrict__ deg, int N,
                                               const int* __restrict__ bsum,
                                               int* __restrict__ offsets,
                                               int* __restrict__ cursor) {
    __shared__ int ts[256];
    int b = blockIdx.x, tid = threadIdx.x;
    int base = b * SCAN_BPB + tid * 4;
    int v[4];
    int s = 0;
#pragma unroll
    for (int i = 0; i < 4; i++) {
        v[i] = (base + i < N) ? deg[base + i] : 0;
        s += v[i];
    }
    ts[tid] = s;
    __syncthreads();
    for (int ofs = 1; ofs < 256; ofs <<= 1) {
        int t = 0;
        if (tid >= ofs) t = ts[tid - ofs];
        __syncthreads();
        ts[tid] += t;
        __syncthreads();
    }
    int run = bsum[b] + ts[tid] - s;           // exclusive prefix for this thread
#pragma unroll
    for (int i = 0; i < 4; i++) {
        if (base + i < N) {
            offsets[base + i] = run;
            cursor[base + i]  = run;
        }
        run += v[i];
    }
}

__global__ void k_scatter(const int* __restrict__ ei, int E, int Et,
                          int* __restrict__ cursor, int* __restrict__ srcs) {
    int i = blockIdx.x * blockDim.x + threadIdx.x;
    if (i < Et) {
        int d = (i < E) ? ei[E + i] : (i - E);
        int s = (i < E) ? ei[i]     : (i - E);
        int pos = atomicAdd(&cursor[d], 1);
        srcs[pos] = s;
    }
}

// ---------------- fused prep: wt1 (transposed bf16) | wt2 | x -> bf16 ----------------

__global__ __launch_bounds__(256) void k_prep(
        const float* __restrict__ Wl1, const float* __restrict__ Wr1,
        ushort* __restrict__ wt1h,
        const float* __restrict__ Wl2, const float* __restrict__ Wr2,
        ushort* __restrict__ wt2h,
        const float* __restrict__ x, ushort* __restrict__ xh,
        int total4) {
    int i = blockIdx.x * blockDim.x + threadIdx.x;
    if (i < 65536) {                       // wt1: c in [0,512) x k in [0,128)
        int c = i >> 7, k = i & 127;
        float v = (c < 256) ? Wl1[k * 256 + c] : Wr1[k * 256 + (c - 256)];
        wt1h[i] = f2b(v);
    } else if (i < 98304) {                // wt2: c in [0,128) x k in [0,256)
        int j = i - 65536;
        int c = j >> 8, k = j & 255;
        float v = (c < 64) ? Wl2[k * 64 + c] : Wr2[k * 64 + (c - 64)];
        wt2h[j] = f2b(v);
    } else {
        int j = i - 98304;
        if (j < total4) {
            float4 v = ((const float4*)x)[j];
            ushort4 h;
            h.x = f2b(v.x); h.y = f2b(v.y); h.z = f2b(v.z); h.w = f2b(v.w);
            ((ushort4*)xh)[j] = h;
        }
    }
}

// ---------------- MFMA GEMM (single-term bf16), weights LDS-resident ----------------
// Block: 128 output cols (col-group = blockIdx.y), grid-stride over 64-row tiles.
// HSLICE: out0 (xl) written head-sliced [8][N][32] (head = col>>5) for L2-resident gather.

template<int K, int HALF, bool HSLICE>
__global__ __launch_bounds__(256) void k_gemm_mfma(
        const ushort* __restrict__ a_hi, int AS,
        const ushort* __restrict__ wt_hi,
        ushort* __restrict__ out0, ushort* __restrict__ out1, int N, int nrt) {
    constexpr int LDK = K + 8;
    __shared__ ushort w_hi[128 * LDK];

    int tid = threadIdx.x;
    int cg  = blockIdx.y;
    const uint4* gh = (const uint4*)(wt_hi + (size_t)cg * 128 * K);
#pragma unroll
    for (int j = 0; j < (128 * K / 8) / 256; j++) {
        int idx = j * 256 + tid;
        int col = idx / (K / 8), k8 = idx % (K / 8);
        *(uint4*)&w_hi[col * LDK + k8 * 8] = gh[idx];
    }
    __syncthreads();

    int wid  = tid >> 6, lane = tid & 63;
    int wrg  = wid & 1;          // row group (32 rows)
    int wcg  = wid >> 1;         // col group (64 cols)
    int r16  = lane & 15, kq = lane >> 4;

    int gcol0 = cg * 128 + wcg * 64;     // wave's 64 cols lie fully in one half
    ushort* dst = (gcol0 < HALF) ? out0 : out1;
    bool slice = HSLICE && (gcol0 < HALF);
    int dcol0 = (gcol0 < HALF) ? gcol0 : gcol0 - HALF;

    for (int rt = blockIdx.x; rt < nrt; rt += gridDim.x) {
        int row0 = rt * 64 + wrg * 32;
        f32x4 acc[2][4];
#pragma unroll
        for (int rh = 0; rh < 2; rh++)
#pragma unroll
            for (int t = 0; t < 4; t++) acc[rh][t] = (f32x4){0.f, 0.f, 0.f, 0.f};

#pragma unroll
        for (int kk = 0; kk < K / 32; kk++) {
            int ko = kk * 32 + kq * 8;
            short8b ah[2];
#pragma unroll
            for (int rh = 0; rh < 2; rh++) {
                int arow = min(row0 + rh * 16 + r16, N - 1);
                ah[rh] = *(const short8b*)(a_hi + (size_t)arow * AS + ko);
            }
#pragma unroll
            for (int t = 0; t < 4; t++) {
                int wcol = wcg * 64 + t * 16 + r16;
                short8b bh = *(const short8b*)&w_hi[wcol * LDK + ko];
#pragma unroll
                for (int rh = 0; rh < 2; rh++)
                    acc[rh][t] = __builtin_amdgcn_mfma_f32_16x16x32_bf16(ah[rh], bh, acc[rh][t], 0, 0, 0);
            }
        }
#pragma unroll
        for (int rh = 0; rh < 2; rh++)
#pragma unroll
            for (int t = 0; t < 4; t++) {
                int col = dcol0 + t * 16 + r16;
                size_t base = slice ? ((size_t)(col >> 5) * N * 32 + (col & 31))
                                    : (size_t)col;
                size_t rstride = slice ? 32 : (size_t)HALF;
#pragma unroll
                for (int r = 0; r < 4; r++) {
                    int row = row0 + rh * 16 + kq * 4 + r;
                    if (row < N) dst[base + (size_t)row * rstride] = f2b(acc[rh][t][r]);
                }
            }
    }
}

// ---------------- Layer 1 fused, head-partitioned: one wave per (node, head) ----------------
// head = blockIdx.y (x-fastest dispatch -> head-major phases; per-head xl table = 3.2MB,
// L2-resident per XCD). Wave: 8 groups x 8 lanes x 4ch; 8 edges/iter; 3-shfl score reduce.
// lrelu(z) = 0.6z + 0.4|z| (exact); no max-subtraction (scores O(1) by construction).

__global__ __launch_bounds__(256) void k_fused1(const int* __restrict__ srcs, int N,
                                                const int* __restrict__ offsets,
                                                const ushort* __restrict__ xlh,  // [8][N][32]
                                                const ushort* __restrict__ xr,   // [N][256]
                                                const float* __restrict__ att,
                                                const float* __restrict__ b1,
                                                ushort* __restrict__ h1) {       // [N][256]
    int node = (blockIdx.x * blockDim.x + threadIdx.x) >> 6;
    int lane = threadIdx.x & 63;
    if (node >= N) return;
    int head = blockIdx.y;
    int g = lane >> 3, l8 = lane & 7;
    int c0 = l8 * 4;                         // channel offset within head

    const ushort* xlt = xlh + (size_t)head * N * 32;

    floatx2 xr2[2], a06[2], a04[2], acc2[2];
    {
        uint2 xraw = *(const uint2*)(xr + (size_t)node * 256 + head * 32 + c0);
        xr2[0] = (floatx2){b2f_lo(xraw.x), b2f_hi(xraw.x)};
        xr2[1] = (floatx2){b2f_lo(xraw.y), b2f_hi(xraw.y)};
    }
    const floatx2* atp = (const floatx2*)(att + head * 32 + c0);
#pragma unroll
    for (int i = 0; i < 2; i++) {
        floatx2 a = atp[i];
        a06[i] = a * 0.6f;
        a04[i] = a * 0.4f;
        acc2[i] = (floatx2){0.f, 0.f};
    }

    int start = offsets[node], end = offsets[node + 1];
    float ssum = 0.f;
    for (int p0 = start; p0 < end; p0 += 64) {
        int cnt = end - p0; if (cnt > 64) cnt = 64;
        int sidx = (lane < cnt) ? srcs[p0 + lane] : 0;   // coalesced batch prefetch
        for (int j = 0; j < cnt; j += 8) {
            int idx = j + g;                              // <= 63 always
            int s = __shfl(sidx, idx);
            uint2 raw = *(const uint2*)(xlt + (size_t)s * 32 + c0);
            floatx2 v[2];
            v[0] = (floatx2){b2f_lo(raw.x), b2f_hi(raw.x)};
            v[1] = (floatx2){b2f_lo(raw.y), b2f_hi(raw.y)};
            floatx2 e2 = (floatx2){0.f, 0.f};
#pragma unroll
            for (int i = 0; i < 2; i++) {
                floatx2 z = v[i] + xr2[i];
                e2 += z * a06[i];
                e2 += __builtin_elementwise_abs(z) * a04[i];
            }
            float e = e2.x + e2.y;
            e += __shfl_xor(e, 1);
            e += __shfl_xor(e, 2);
            e += __shfl_xor(e, 4);                        // head score (8-lane group)
            float w = (idx < cnt) ? __expf(e) : 0.f;
            ssum += w;
            floatx2 w2 = (floatx2){w, w};
#pragma unroll
            for (int i = 0; i < 2; i++) acc2[i] += v[i] * w2;
        }
    }
    // merge the 8 edge-groups (lanes with same l8)
    ssum += __shfl_xor(ssum, 8);
    ssum += __shfl_xor(ssum, 16);
    ssum += __shfl_xor(ssum, 32);
#pragma unroll
    for (int i = 0; i < 2; i++) {
        acc2[i].x += __shfl_xor(acc2[i].x, 8);
        acc2[i].x += __shfl_xor(acc2[i].x, 16);
        acc2[i].x += __shfl_xor(acc2[i].x, 32);
        acc2[i].y += __shfl_xor(acc2[i].y, 8);
        acc2[i].y += __shfl_xor(acc2[i].y, 16);
        acc2[i].y += __shfl_xor(acc2[i].y, 32);
    }

    if (g == 0) {
        const floatx2* bvp = (const floatx2*)(b1 + head * 32 + c0);
        float inv = 1.f / ssum;
        ushort oh[4];
#pragma unroll
        for (int i = 0; i < 2; i++) {
            floatx2 bv = bvp[i];
            oh[2*i]   = f2b(elu1(acc2[i].x * inv + bv.x));
            oh[2*i+1] = f2b(elu1(acc2[i].y * inv + bv.y));
        }
        *(uint2*)(h1 + (size_t)node * 256 + head * 32 + c0) = *(uint2*)oh;
    }
}

// ---------------- Layer 2 fused (final output), one wave/node, 4 edges/iter ----------------

__global__ __launch_bounds__(256) void k_fused2(const int* __restrict__ srcs, int N,
                                                const int* __restrict__ offsets,
                                                const ushort* __restrict__ xl,
                                                const ushort* __restrict__ xr,
                                                const float* __restrict__ att,
                                                const float* __restrict__ b2,
                                                float* __restrict__ out) {
    int wid  = (blockIdx.x * blockDim.x + threadIdx.x) >> 6;
    int lane = threadIdx.x & 63;
    if (wid >= N) return;
    int start = offsets[wid], end = offsets[wid + 1];
    int g = lane >> 4, l4 = lane & 15;
    int c0 = l4 * 4;

    floatx2 xr2[2], a06[2], a04[2], acc2[2];
    {
        uint2 xraw = *(const uint2*)(xr + (size_t)wid * 64 + c0);
        xr2[0] = (floatx2){b2f_lo(xraw.x), b2f_hi(xraw.x)};
        xr2[1] = (floatx2){b2f_lo(xraw.y), b2f_hi(xraw.y)};
    }
    const floatx2* atp = (const floatx2*)(att + c0);
#pragma unroll
    for (int i = 0; i < 2; i++) {
        floatx2 a = atp[i];
        a06[i] = a * 0.6f;
        a04[i] = a * 0.4f;
        acc2[i] = (floatx2){0.f, 0.f};
    }

    float ssum = 0.f;
    const ushort* xlp = xl + c0;
    for (int p0 = start; p0 < end; p0 += 64) {
        int cnt = end - p0; if (cnt > 64) cnt = 64;
        int sidx = (lane < cnt) ? srcs[p0 + lane] : 0;
        for (int j = 0; j < cnt; j += 4) {
            int idx = j + g;                              // <= 63 always
            int s = __shfl(sidx, idx);
            uint2 raw = *(const uint2*)(xlp + (size_t)s * 64);
            floatx2 v[2];
            v[0] = (floatx2){b2f_lo(raw.x), b2f_hi(raw.x)};
            v[1] = (floatx2){b2f_lo(raw.y), b2f_hi(raw.y)};
            floatx2 e2 = (floatx2){0.f, 0.f};
#pragma unroll
            for (int i = 0; i < 2; i++) {
                floatx2 z = v[i] + xr2[i];
                e2 += z * a06[i];
                e2 += __builtin_elementwise_abs(z) * a04[i];
            }
            float e = e2.x + e2.y;
            e += __shfl_xor(e, 1);
            e += __shfl_xor(e, 2);
            e += __shfl_xor(e, 4);
            e += __shfl_xor(e, 8);                        // full 64-ch score (16-lane group)
            float w = (idx < cnt) ? __expf(e) : 0.f;
            ssum += w;
            floatx2 w2 = (floatx2){w, w};
#pragma unroll
            for (int i = 0; i < 2; i++) acc2[i] += v[i] * w2;
        }
    }
    // merge the four edge-groups
    ssum += __shfl_xor(ssum, 16);
    ssum += __shfl_xor(ssum, 32);
#pragma unroll
    for (int i = 0; i < 2; i++) {
        acc2[i].x += __shfl_xor(acc2[i].x, 16);
        acc2[i].x += __shfl_xor(acc2[i].x, 32);
        acc2[i].y += __shfl_xor(acc2[i].y, 16);
        acc2[i].y += __shfl_xor(acc2[i].y, 32);
    }
    if (g == 0) {
        float4 bv = *(const float4*)(b2 + c0);
        float inv = 1.f / ssum;
        float4 o;
        o.x = acc2[0].x * inv + bv.x;
        o.y = acc2[0].y * inv + bv.y;
        o.z = acc2[1].x * inv + bv.z;
        o.w = acc2[1].y * inv + bv.w;
        *(float4*)(out + (size_t)wid * 64 + c0) = o;
    }
}

// ---------------- launch ----------------

extern "C" void kernel_launch(void* const* d_in, const int* in_sizes, int n_in,
                              void* d_out, int out_size, void* d_ws, size_t ws_size,
                              hipStream_t stream) {
    const float* x    = (const float*)d_in[0];
    const int*   ei   = (const int*)d_in[1];
    // d_in[2] edge_type unused by forward
    const float* Wl1  = (const float*)d_in[3];
    const float* Wr1  = (const float*)d_in[4];
    const float* att1 = (const float*)d_in[5];
    const float* b1   = (const float*)d_in[6];
    const float* Wl2  = (const float*)d_in[7];
    const float* Wr2  = (const float*)d_in[8];
    const float* att2 = (const float*)d_in[9];
    const float* b2   = (const float*)d_in[10];
    float* out = (float*)d_out;

    const int N  = in_sizes[0] / 128;  // 50000
    const int E  = in_sizes[1] / 2;    // 800000
    const int Et = E + N;              // with self loops
    const int nrt = (N + 63) / 64;     // 64-row tiles
    const int nsb = (N + SCAN_BPB - 1) / SCAN_BPB;  // scan blocks (49) — must be <= 256

    // ---- workspace layout ----
    char* ws = (char*)d_ws;
    size_t off = 0;
    auto alloc = [&](size_t bytes) { size_t o = off; off += (bytes + 255) & ~(size_t)255; return o; };
    size_t o_xl1     = alloc((size_t)N * 256 * 2);   // bf16, head-sliced [8][N][32]
    size_t o_xr1     = alloc((size_t)N * 256 * 2);   // bf16 [N][256]
    size_t o_h1      = alloc((size_t)N * 256 * 2);   // bf16 [N][256]
    size_t o_offsets = alloc((size_t)(N + 1) * 4);
    size_t o_deg     = alloc((size_t)N * 4);
    size_t o_cursor  = alloc((size_t)N * 4);
    size_t o_srcs    = alloc((size_t)Et * 4);
    size_t o_bsum    = alloc((size_t)256 * 4);
    size_t o_wt1h    = alloc((size_t)512 * 128 * 2);
    size_t o_wt2h    = alloc((size_t)128 * 256 * 2);
    size_t o_xh      = alloc((size_t)N * 128 * 2);
    size_t o_xl2     = alloc((size_t)N * 64 * 2);    // bf16
    size_t o_xr2     = alloc((size_t)N * 64 * 2);    // bf16
    (void)ws_size;

    ushort* xl1     = (ushort*)(ws + o_xl1);
    ushort* xr1     = (ushort*)(ws + o_xr1);
    ushort* h1      = (ushort*)(ws + o_h1);
    int*    offsets = (int*)(ws + o_offsets);
    int*    deg     = (int*)(ws + o_deg);
    int*    cursor  = (int*)(ws + o_cursor);
    int*    srcs    = (int*)(ws + o_srcs);
    int*    bsum    = (int*)(ws + o_bsum);
    ushort* wt1h    = (ushort*)(ws + o_wt1h);
    ushort* wt2h    = (ushort*)(ws + o_wt2h);
    ushort* xh      = (ushort*)(ws + o_xh);
    ushort* xl2     = (ushort*)(ws + o_xl2);
    ushort* xr2     = (ushort*)(ws + o_xr2);

    // ---- CSR build + fused prep (independent of GEMMs) ----
    hipMemsetAsync(deg, 0, (size_t)N * 4, stream);
    int tb = 256;
    k_hist<<<(Et + tb - 1) / tb, tb, 0, stream>>>(ei, E, Et, deg);
    k_scan1<<<nsb, 256, 0, stream>>>(deg, N, bsum);
    k_scan2<<<1, 256, 0, stream>>>(bsum, nsb, offsets, N);
    k_scan3<<<nsb, 256, 0, stream>>>(deg, N, bsum, offsets, cursor);
    k_scatter<<<(Et + tb - 1) / tb, tb, 0, stream>>>(ei, E, Et, cursor, srcs);
    int total4 = N * 128 / 4;
    int prep_items = 98304 + total4;
    k_prep<<<(prep_items + 255) / 256, 256, 0, stream>>>(Wl1, Wr1, wt1h,
                                                         Wl2, Wr2, wt2h,
                                                         x, xh, total4);

    // ---- layer 1: A = xh (stride 128), 4 col-groups of 128 over 512 cols ----
    k_gemm_mfma<128, 256, true><<<dim3(256, 4), 256, 0, stream>>>(xh, 128, wt1h, xl1, xr1, N, nrt);
    k_fused1<<<dim3((N + 3) / 4, 8), 256, 0, stream>>>(srcs, N, offsets, xl1, xr1, att1, b1, h1);

    // ---- layer 2: A = h1 bf16 (stride 256), 1 col-group of 128 ----
    k_gemm_mfma<256, 64, false><<<dim3(392, 1), 256, 0, stream>>>(h1, 256, wt2h, xl2, xr2, N, nrt);
    k_fused2<<<(N + 3) / 4, 256, 0, stream>>>(srcs, N, offsets, xl2, xr2, att2, b2, out);
}

// Round 12
// 248.333 us; speedup vs baseline: 1.4683x; 1.4683x over previous
//
#include <hip/hip_runtime.h>
#include <math.h>

__device__ __forceinline__ float elu1(float z)  { return z > 0.f ? z : (__expf(z) - 1.f); }

// bf16 helpers (RTN-even)
__device__ __forceinline__ ushort f2b(float f) {
    uint u = __float_as_uint(f);
    uint r = (u + 0x7FFFu + ((u >> 16) & 1u)) >> 16;
    return (ushort)r;
}
__device__ __forceinline__ float b2f(ushort h) { return __uint_as_float(((uint)h) << 16); }
__device__ __forceinline__ float b2f_lo(uint u) { return __uint_as_float(u << 16); }
__device__ __forceinline__ float b2f_hi(uint u) { return __uint_as_float(u & 0xFFFF0000u); }

typedef __attribute__((ext_vector_type(8))) short short8b;   // 8 bf16 = 4 VGPRs (MFMA A/B frag)
typedef __attribute__((ext_vector_type(4))) float f32x4;     // MFMA C/D frag
typedef __attribute__((ext_vector_type(2))) float floatx2;   // packed fp32 (v_pk_*)

#define SCAN_BPB 1024   // elements per scan block (256 threads x 4)

// ---- two-level scan ----

__global__ __launch_bounds__(256) void k_scan1(const int* __restrict__ deg, int N,
                                               int* __restrict__ bsum) {
    __shared__ int ts[256];
    int b = blockIdx.x, tid = threadIdx.x;
    int base = b * SCAN_BPB + tid * 4;
    int s = 0;
    if (base + 3 < N) {
        int4 v = *(const int4*)(deg + base);
        s = v.x + v.y + v.z + v.w;
    } else {
        for (int i = 0; i < 4; i++) if (base + i < N) s += deg[base + i];
    }
    ts[tid] = s;
    __syncthreads();
    for (int ofs = 128; ofs > 0; ofs >>= 1) {
        if (tid < ofs) ts[tid] += ts[tid + ofs];
        __syncthreads();
    }
    if (tid == 0) bsum[b] = ts[0];
}

__global__ __launch_bounds__(256) void k_scan2(int* __restrict__ bsum, int nb,
                                               int* __restrict__ offsets, int N) {
    __shared__ int sums[256];
    int tid = threadIdx.x;
    int v = (tid < nb) ? bsum[tid] : 0;
    sums[tid] = v;
    __syncthreads();
    for (int ofs = 1; ofs < 256; ofs <<= 1) {
        int t = 0;
        if (tid >= ofs) t = sums[tid - ofs];
        __syncthreads();
        sums[tid] += t;
        __syncthreads();
    }
    if (tid < nb) bsum[tid] = sums[tid] - v;   // exclusive
    if (tid == 255) offsets[N] = sums[255];    // grand total
}

__global__ __launch_bounds__(256) void k_scan3(const int* __restrict__ deg, int N,
                                               const int* __restrict__ bsum,
                                               int* __restrict__ offsets,
                                               int* __restrict__ cursor) {
    __shared__ int ts[256];
    int b = blockIdx.x, tid = threadIdx.x;
    int base = b * SCAN_BPB + tid * 4;
    int v[4];
    int s = 0;
#pragma unroll
    for (int i = 0; i < 4; i++) {
        v[i] = (base + i < N) ? deg[base + i] : 0;
        s += v[i];
    }
    ts[tid] = s;
    __syncthreads();
    for (int ofs = 1; ofs < 256; ofs <<= 1) {
        int t = 0;
        if (tid >= ofs) t = ts[tid - ofs];
        __syncthreads();
        ts[tid] += t;
        __syncthreads();
    }
    int run = bsum[b] + ts[tid] - s;           // exclusive prefix for this thread
#pragma unroll
    for (int i = 0; i < 4; i++) {
        if (base + i < N) {
            offsets[base + i] = run;
            cursor[base + i]  = run;
        }
        run += v[i];
    }
}

__global__ void k_scatter(const int* __restrict__ ei, int E, int Et,
                          int* __restrict__ cursor, int* __restrict__ srcs) {
    int i = blockIdx.x * blockDim.x + threadIdx.x;
    if (i < Et) {
        int d = (i < E) ? ei[E + i] : (i - E);
        int s = (i < E) ? ei[i]     : (i - E);
        int pos = atomicAdd(&cursor[d], 1);
        srcs[pos] = s;
    }
}

// ---------------- fused prep: hist | wt1 (transposed bf16) | wt2 | x -> bf16 ----------------

__global__ __launch_bounds__(256) void k_prep(
        const int* __restrict__ ei, int E, int Et, int* __restrict__ deg,
        const float* __restrict__ Wl1, const float* __restrict__ Wr1,
        ushort* __restrict__ wt1h,
        const float* __restrict__ Wl2, const float* __restrict__ Wr2,
        ushort* __restrict__ wt2h,
        const float* __restrict__ x, ushort* __restrict__ xh,
        int total4) {
    int i = blockIdx.x * blockDim.x + threadIdx.x;
    if (i < Et) {                          // degree histogram (self-loop edges: dst = i - E)
        int d = (i < E) ? ei[E + i] : (i - E);
        atomicAdd(&deg[d], 1);
        return;
    }
    int p = i - Et;
    if (p < 65536) {                       // wt1: c in [0,512) x k in [0,128)
        int c = p >> 7, k = p & 127;
        float v = (c < 256) ? Wl1[k * 256 + c] : Wr1[k * 256 + (c - 256)];
        wt1h[p] = f2b(v);
    } else if (p < 98304) {                // wt2: c in [0,128) x k in [0,256)
        int j = p - 65536;
        int c = j >> 8, k = j & 255;
        float v = (c < 64) ? Wl2[k * 64 + c] : Wr2[k * 64 + (c - 64)];
        wt2h[j] = f2b(v);
    } else {
        int j = p - 98304;
        if (j < total4) {
            float4 v = ((const float4*)x)[j];
            ushort4 h;
            h.x = f2b(v.x); h.y = f2b(v.y); h.z = f2b(v.z); h.w = f2b(v.w);
            ((ushort4*)xh)[j] = h;
        }
    }
}

// ---------------- MFMA GEMM (single-term bf16), weights LDS-resident ----------------
// Block: 128 output cols (col-group = blockIdx.y), grid-stride over 64-row tiles.
// 4 waves = 2 row-groups(32) x 2 col-groups(64). Wave: acc[2][4] 16x16 tiles.
// Both output halves stored bf16 (out0 = cols < HALF, out1 = cols >= HALF).

template<int K, int HALF>
__global__ __launch_bounds__(256) void k_gemm_mfma(
        const ushort* __restrict__ a_hi, int AS,
        const ushort* __restrict__ wt_hi,
        ushort* __restrict__ out0, ushort* __restrict__ out1, int N, int nrt) {
    constexpr int LDK = K + 8;
    __shared__ ushort w_hi[128 * LDK];

    int tid = threadIdx.x;
    int cg  = blockIdx.y;
    const uint4* gh = (const uint4*)(wt_hi + (size_t)cg * 128 * K);
#pragma unroll
    for (int j = 0; j < (128 * K / 8) / 256; j++) {
        int idx = j * 256 + tid;
        int col = idx / (K / 8), k8 = idx % (K / 8);
        *(uint4*)&w_hi[col * LDK + k8 * 8] = gh[idx];
    }
    __syncthreads();

    int wid  = tid >> 6, lane = tid & 63;
    int wrg  = wid & 1;          // row group (32 rows)
    int wcg  = wid >> 1;         // col group (64 cols)
    int r16  = lane & 15, kq = lane >> 4;

    int gcol0 = cg * 128 + wcg * 64;     // wave's 64 cols lie fully in one half
    ushort* dst = (gcol0 < HALF) ? out0 : out1;
    int dcol0 = (gcol0 < HALF) ? gcol0 : gcol0 - HALF;

    for (int rt = blockIdx.x; rt < nrt; rt += gridDim.x) {
        int row0 = rt * 64 + wrg * 32;
        f32x4 acc[2][4];
#pragma unroll
        for (int rh = 0; rh < 2; rh++)
#pragma unroll
            for (int t = 0; t < 4; t++) acc[rh][t] = (f32x4){0.f, 0.f, 0.f, 0.f};

#pragma unroll
        for (int kk = 0; kk < K / 32; kk++) {
            int ko = kk * 32 + kq * 8;
            short8b ah[2];
#pragma unroll
            for (int rh = 0; rh < 2; rh++) {
                int arow = min(row0 + rh * 16 + r16, N - 1);
                ah[rh] = *(const short8b*)(a_hi + (size_t)arow * AS + ko);
            }
#pragma unroll
            for (int t = 0; t < 4; t++) {
                int wcol = wcg * 64 + t * 16 + r16;
                short8b bh = *(const short8b*)&w_hi[wcol * LDK + ko];
#pragma unroll
                for (int rh = 0; rh < 2; rh++)
                    acc[rh][t] = __builtin_amdgcn_mfma_f32_16x16x32_bf16(ah[rh], bh, acc[rh][t], 0, 0, 0);
            }
        }
#pragma unroll
        for (int rh = 0; rh < 2; rh++)
#pragma unroll
            for (int t = 0; t < 4; t++)
#pragma unroll
                for (int r = 0; r < 4; r++) {
                    int row = row0 + rh * 16 + kq * 4 + r;
                    if (row < N)
                        dst[(size_t)row * HALF + dcol0 + t * 16 + r16] = f2b(acc[rh][t][r]);
                }
    }
}

// ---------------- Layer 1 fused: scores + softmax + aggregate, one wave/node, 2 edges/iter ----
// No max-subtraction (scores O(1) by construction). lrelu(z) = 0.6z + 0.4|z| (exact).
// xl, xr both bf16 (512B rows); h1 written as plain bf16 (separate buffer).

__global__ __launch_bounds__(256) void k_fused1(const int* __restrict__ srcs, int N,
                                                const int* __restrict__ offsets,
                                                const ushort* __restrict__ xl,
                                                const ushort* __restrict__ xr,
                                                const float* __restrict__ att,
                                                const float* __restrict__ b1,
                                                ushort* __restrict__ h1) {
    int wid  = (blockIdx.x * blockDim.x + threadIdx.x) >> 6;
    int lane = threadIdx.x & 63;
    if (wid >= N) return;
    int start = offsets[wid], end = offsets[wid + 1];
    int g = lane >> 5, l5 = lane & 31;
    int c0 = l5 * 8;

    floatx2 xr2[4], a06[4], a04[4], acc2[4];
    {
        uint4 xraw = *(const uint4*)(xr + (size_t)wid * 256 + c0);
        xr2[0] = (floatx2){b2f_lo(xraw.x), b2f_hi(xraw.x)};
        xr2[1] = (floatx2){b2f_lo(xraw.y), b2f_hi(xraw.y)};
        xr2[2] = (floatx2){b2f_lo(xraw.z), b2f_hi(xraw.z)};
        xr2[3] = (floatx2){b2f_lo(xraw.w), b2f_hi(xraw.w)};
    }
    const floatx2* atp = (const floatx2*)(att + c0);
#pragma unroll
    for (int i = 0; i < 4; i++) {
        floatx2 a = atp[i];
        a06[i] = a * 0.6f;
        a04[i] = a * 0.4f;
        acc2[i] = (floatx2){0.f, 0.f};
    }

    float ssum = 0.f;
    const ushort* xlp = xl + c0;
    for (int p0 = start; p0 < end; p0 += 64) {
        int cnt = end - p0; if (cnt > 64) cnt = 64;
        int sidx = (lane < cnt) ? srcs[p0 + lane] : 0;   // coalesced batch prefetch
        for (int j = 0; j < cnt; j += 2) {
            int idx = j + g;                              // <= 63 always
            int s = __shfl(sidx, idx);
            uint4 raw = *(const uint4*)(xlp + (size_t)s * 256);
            floatx2 v[4];
            v[0] = (floatx2){b2f_lo(raw.x), b2f_hi(raw.x)};
            v[1] = (floatx2){b2f_lo(raw.y), b2f_hi(raw.y)};
            v[2] = (floatx2){b2f_lo(raw.z), b2f_hi(raw.z)};
            v[3] = (floatx2){b2f_lo(raw.w), b2f_hi(raw.w)};
            floatx2 e2 = (floatx2){0.f, 0.f};
#pragma unroll
            for (int i = 0; i < 4; i++) {
                floatx2 z = v[i] + xr2[i];
                e2 += z * a06[i];
                e2 += __builtin_elementwise_abs(z) * a04[i];
            }
            float e = e2.x + e2.y;
            e += __shfl_xor(e, 1);
            e += __shfl_xor(e, 2);                        // head score (4-lane group)
            float w = (idx < cnt) ? __expf(e) : 0.f;
            ssum += w;
            floatx2 w2 = (floatx2){w, w};
#pragma unroll
            for (int i = 0; i < 4; i++) acc2[i] += v[i] * w2;
        }
    }
    // merge the two edge-groups
    ssum += __shfl_xor(ssum, 32);
#pragma unroll
    for (int i = 0; i < 4; i++) {
        acc2[i].x += __shfl_xor(acc2[i].x, 32);
        acc2[i].y += __shfl_xor(acc2[i].y, 32);
    }

    if (g == 0) {
        const floatx2* bvp = (const floatx2*)(b1 + c0);
        float inv = 1.f / ssum;
        ushort oh[8];
#pragma unroll
        for (int i = 0; i < 4; i++) {
            floatx2 bv = bvp[i];
            oh[2*i]   = f2b(elu1(acc2[i].x * inv + bv.x));
            oh[2*i+1] = f2b(elu1(acc2[i].y * inv + bv.y));
        }
        *(uint4*)(h1 + (size_t)wid * 256 + c0) = *(uint4*)oh;
    }
}

// ---------------- Layer 2 fused (final output), one wave/node, 4 edges/iter ----------------

__global__ __launch_bounds__(256) void k_fused2(const int* __restrict__ srcs, int N,
                                                const int* __restrict__ offsets,
                                                const ushort* __restrict__ xl,
                                                const ushort* __restrict__ xr,
                                                const float* __restrict__ att,
                                                const float* __restrict__ b2,
                                                float* __restrict__ out) {
    int wid  = (blockIdx.x * blockDim.x + threadIdx.x) >> 6;
    int lane = threadIdx.x & 63;
    if (wid >= N) return;
    int start = offsets[wid], end = offsets[wid + 1];
    int g = lane >> 4, l4 = lane & 15;
    int c0 = l4 * 4;

    floatx2 xr2[2], a06[2], a04[2], acc2[2];
    {
        uint2 xraw = *(const uint2*)(xr + (size_t)wid * 64 + c0);
        xr2[0] = (floatx2){b2f_lo(xraw.x), b2f_hi(xraw.x)};
        xr2[1] = (floatx2){b2f_lo(xraw.y), b2f_hi(xraw.y)};
    }
    const floatx2* atp = (const floatx2*)(att + c0);
#pragma unroll
    for (int i = 0; i < 2; i++) {
        floatx2 a = atp[i];
        a06[i] = a * 0.6f;
        a04[i] = a * 0.4f;
        acc2[i] = (floatx2){0.f, 0.f};
    }

    float ssum = 0.f;
    const ushort* xlp = xl + c0;
    for (int p0 = start; p0 < end; p0 += 64) {
        int cnt = end - p0; if (cnt > 64) cnt = 64;
        int sidx = (lane < cnt) ? srcs[p0 + lane] : 0;
        for (int j = 0; j < cnt; j += 4) {
            int idx = j + g;                              // <= 63 always
            int s = __shfl(sidx, idx);
            uint2 raw = *(const uint2*)(xlp + (size_t)s * 64);
            floatx2 v[2];
            v[0] = (floatx2){b2f_lo(raw.x), b2f_hi(raw.x)};
            v[1] = (floatx2){b2f_lo(raw.y), b2f_hi(raw.y)};
            floatx2 e2 = (floatx2){0.f, 0.f};
#pragma unroll
            for (int i = 0; i < 2; i++) {
                floatx2 z = v[i] + xr2[i];
                e2 += z * a06[i];
                e2 += __builtin_elementwise_abs(z) * a04[i];
            }
            float e = e2.x + e2.y;
            e += __shfl_xor(e, 1);
            e += __shfl_xor(e, 2);
            e += __shfl_xor(e, 4);
            e += __shfl_xor(e, 8);                        // full 64-ch score (16-lane group)
            float w = (idx < cnt) ? __expf(e) : 0.f;
            ssum += w;
            floatx2 w2 = (floatx2){w, w};
#pragma unroll
            for (int i = 0; i < 2; i++) acc2[i] += v[i] * w2;
        }
    }
    // merge the four edge-groups
    ssum += __shfl_xor(ssum, 16);
    ssum += __shfl_xor(ssum, 32);
#pragma unroll
    for (int i = 0; i < 2; i++) {
        acc2[i].x += __shfl_xor(acc2[i].x, 16);
        acc2[i].x += __shfl_xor(acc2[i].x, 32);
        acc2[i].y += __shfl_xor(acc2[i].y, 16);
        acc2[i].y += __shfl_xor(acc2[i].y, 32);
    }
    if (g == 0) {
        float4 bv = *(const float4*)(b2 + c0);
        float inv = 1.f / ssum;
        float4 o;
        o.x = acc2[0].x * inv + bv.x;
        o.y = acc2[0].y * inv + bv.y;
        o.z = acc2[1].x * inv + bv.z;
        o.w = acc2[1].y * inv + bv.w;
        *(float4*)(out + (size_t)wid * 64 + c0) = o;
    }
}

// ---------------- launch ----------------

extern "C" void kernel_launch(void* const* d_in, const int* in_sizes, int n_in,
                              void* d_out, int out_size, void* d_ws, size_t ws_size,
                              hipStream_t stream) {
    const float* x    = (const float*)d_in[0];
    const int*   ei   = (const int*)d_in[1];
    // d_in[2] edge_type unused by forward
    const float* Wl1  = (const float*)d_in[3];
    const float* Wr1  = (const float*)d_in[4];
    const float* att1 = (const float*)d_in[5];
    const float* b1   = (const float*)d_in[6];
    const float* Wl2  = (const float*)d_in[7];
    const float* Wr2  = (const float*)d_in[8];
    const float* att2 = (const float*)d_in[9];
    const float* b2   = (const float*)d_in[10];
    float* out = (float*)d_out;

    const int N  = in_sizes[0] / 128;  // 50000
    const int E  = in_sizes[1] / 2;    // 800000
    const int Et = E + N;              // with self loops
    const int nrt = (N + 63) / 64;     // 64-row tiles
    const int nsb = (N + SCAN_BPB - 1) / SCAN_BPB;  // scan blocks (49) — must be <= 256

    // ---- workspace layout ----
    char* ws = (char*)d_ws;
    size_t off = 0;
    auto alloc = [&](size_t bytes) { size_t o = off; off += (bytes + 255) & ~(size_t)255; return o; };
    size_t o_xl1     = alloc((size_t)N * 256 * 2);   // bf16
    size_t o_xr1     = alloc((size_t)N * 256 * 2);   // bf16
    size_t o_h1      = alloc((size_t)N * 256 * 2);   // bf16
    size_t o_offsets = alloc((size_t)(N + 1) * 4);
    size_t o_deg     = alloc((size_t)N * 4);
    size_t o_cursor  = alloc((size_t)N * 4);
    size_t o_srcs    = alloc((size_t)Et * 4);
    size_t o_bsum    = alloc((size_t)256 * 4);
    size_t o_wt1h    = alloc((size_t)512 * 128 * 2);
    size_t o_wt2h    = alloc((size_t)128 * 256 * 2);
    size_t o_xh      = alloc((size_t)N * 128 * 2);
    size_t o_xl2     = alloc((size_t)N * 64 * 2);    // bf16
    size_t o_xr2     = alloc((size_t)N * 64 * 2);    // bf16
    (void)ws_size;

    ushort* xl1     = (ushort*)(ws + o_xl1);
    ushort* xr1     = (ushort*)(ws + o_xr1);
    ushort* h1      = (ushort*)(ws + o_h1);
    int*    offsets = (int*)(ws + o_offsets);
    int*    deg     = (int*)(ws + o_deg);
    int*    cursor  = (int*)(ws + o_cursor);
    int*    srcs    = (int*)(ws + o_srcs);
    int*    bsum    = (int*)(ws + o_bsum);
    ushort* wt1h    = (ushort*)(ws + o_wt1h);
    ushort* wt2h    = (ushort*)(ws + o_wt2h);
    ushort* xh      = (ushort*)(ws + o_xh);
    ushort* xl2     = (ushort*)(ws + o_xl2);
    ushort* xr2     = (ushort*)(ws + o_xr2);

    // ---- CSR build + fused prep ----
    hipMemsetAsync(deg, 0, (size_t)N * 4, stream);
    int tb = 256;
    int total4 = N * 128 / 4;
    int prep_items = Et + 98304 + total4;
    k_prep<<<(prep_items + tb - 1) / tb, tb, 0, stream>>>(ei, E, Et, deg,
                                                          Wl1, Wr1, wt1h,
                                                          Wl2, Wr2, wt2h,
                                                          x, xh, total4);
    k_scan1<<<nsb, 256, 0, stream>>>(deg, N, bsum);
    k_scan2<<<1, 256, 0, stream>>>(bsum, nsb, offsets, N);
    k_scan3<<<nsb, 256, 0, stream>>>(deg, N, bsum, offsets, cursor);
    k_scatter<<<(Et + tb - 1) / tb, tb, 0, stream>>>(ei, E, Et, cursor, srcs);

    // ---- layer 1: A = xh (stride 128), 4 col-groups of 128 over 512 cols ----
    k_gemm_mfma<128, 256><<<dim3(256, 4), 256, 0, stream>>>(xh, 128, wt1h, xl1, xr1, N, nrt);
    k_fused1<<<(N + 3) / 4, 256, 0, stream>>>(srcs, N, offsets, xl1, xr1, att1, b1, h1);

    // ---- layer 2: A = h1 bf16 (stride 256), 1 col-group of 128 ----
    k_gemm_mfma<256, 64><<<dim3(392, 1), 256, 0, stream>>>(h1, 256, wt2h, xl2, xr2, N, nrt);
    k_fused2<<<(N + 3) / 4, 256, 0, stream>>>(srcs, N, offsets, xl2, xr2, att2, b2, out);
}

// Round 13
// 241.123 us; speedup vs baseline: 1.5122x; 1.0299x over previous
//
#include <hip/hip_runtime.h>
#include <math.h>

__device__ __forceinline__ float elu1(float z)  { return z > 0.f ? z : (__expf(z) - 1.f); }

// bf16 helpers (RTN-even)
__device__ __forceinline__ ushort f2b(float f) {
    uint u = __float_as_uint(f);
    uint r = (u + 0x7FFFu + ((u >> 16) & 1u)) >> 16;
    return (ushort)r;
}
__device__ __forceinline__ float b2f(ushort h) { return __uint_as_float(((uint)h) << 16); }
__device__ __forceinline__ float b2f_lo(uint u) { return __uint_as_float(u << 16); }
__device__ __forceinline__ float b2f_hi(uint u) { return __uint_as_float(u & 0xFFFF0000u); }

typedef __attribute__((ext_vector_type(8))) short short8b;   // 8 bf16 = 4 VGPRs (MFMA A/B frag)
typedef __attribute__((ext_vector_type(4))) float f32x4;     // MFMA C/D frag
typedef __attribute__((ext_vector_type(2))) float floatx2;   // packed fp32 (v_pk_*)

#define SCAN_BPB 1024   // elements per scan block (256 threads x 4)

// ---- two-level scan (scan2 folded into scan3: each block redundantly reduces its base) ----

__global__ __launch_bounds__(256) void k_scan1(const int* __restrict__ deg, int N,
                                               int* __restrict__ bsum) {
    __shared__ int ts[256];
    int b = blockIdx.x, tid = threadIdx.x;
    int base = b * SCAN_BPB + tid * 4;
    int s = 0;
    if (base + 3 < N) {
        int4 v = *(const int4*)(deg + base);
        s = v.x + v.y + v.z + v.w;
    } else {
        for (int i = 0; i < 4; i++) if (base + i < N) s += deg[base + i];
    }
    ts[tid] = s;
    __syncthreads();
    for (int ofs = 128; ofs > 0; ofs >>= 1) {
        if (tid < ofs) ts[tid] += ts[tid + ofs];
        __syncthreads();
    }
    if (tid == 0) bsum[b] = ts[0];
}

__global__ __launch_bounds__(256) void k_scan3(const int* __restrict__ deg, int N,
                                               const int* __restrict__ bsum, int nb,
                                               int* __restrict__ offsets,
                                               int* __restrict__ cursor) {
    __shared__ int ts[256];
    __shared__ int bs[256];
    int b = blockIdx.x, tid = threadIdx.x;
    // base = sum of bsum[0..b) (redundant per-block reduce over <=256 entries)
    bs[tid] = (tid < nb && tid < b) ? bsum[tid] : 0;
    __syncthreads();
    for (int ofs = 128; ofs > 0; ofs >>= 1) {
        if (tid < ofs) bs[tid] += bs[tid + ofs];
        __syncthreads();
    }
    int base = bs[0];

    int gbase = b * SCAN_BPB + tid * 4;
    int v[4];
    int s = 0;
#pragma unroll
    for (int i = 0; i < 4; i++) {
        v[i] = (gbase + i < N) ? deg[gbase + i] : 0;
        s += v[i];
    }
    ts[tid] = s;
    __syncthreads();
    for (int ofs = 1; ofs < 256; ofs <<= 1) {
        int t = 0;
        if (tid >= ofs) t = ts[tid - ofs];
        __syncthreads();
        ts[tid] += t;
        __syncthreads();
    }
    int run = base + ts[tid] - s;              // exclusive prefix for this thread
#pragma unroll
    for (int i = 0; i < 4; i++) {
        if (gbase + i < N) {
            offsets[gbase + i] = run;
            cursor[gbase + i]  = run;
        }
        run += v[i];
    }
    if (b == nb - 1 && tid == 255) offsets[N] = base + ts[255];   // grand total
}

__global__ void k_scatter(const int* __restrict__ ei, int E, int Et,
                          int* __restrict__ cursor, int* __restrict__ srcs) {
    int i = blockIdx.x * blockDim.x + threadIdx.x;
    if (i < Et) {
        int d = (i < E) ? ei[E + i] : (i - E);
        int s = (i < E) ? ei[i]     : (i - E);
        int pos = atomicAdd(&cursor[d], 1);
        srcs[pos] = s;
    }
}

// ---------------- fused prep: hist | wt1 (transposed bf16) | wt2 | x -> bf16 ----------------

__global__ __launch_bounds__(256) void k_prep(
        const int* __restrict__ ei, int E, int Et, int* __restrict__ deg,
        const float* __restrict__ Wl1, const float* __restrict__ Wr1,
        ushort* __restrict__ wt1h,
        const float* __restrict__ Wl2, const float* __restrict__ Wr2,
        ushort* __restrict__ wt2h,
        const float* __restrict__ x, ushort* __restrict__ xh,
        int total4) {
    int i = blockIdx.x * blockDim.x + threadIdx.x;
    if (i < Et) {                          // degree histogram (self-loop edges: dst = i - E)
        int d = (i < E) ? ei[E + i] : (i - E);
        atomicAdd(&deg[d], 1);
        return;
    }
    int p = i - Et;
    if (p < 65536) {                       // wt1: c in [0,512) x k in [0,128)
        int c = p >> 7, k = p & 127;
        float v = (c < 256) ? Wl1[k * 256 + c] : Wr1[k * 256 + (c - 256)];
        wt1h[p] = f2b(v);
    } else if (p < 98304) {                // wt2: c in [0,128) x k in [0,256)
        int j = p - 65536;
        int c = j >> 8, k = j & 255;
        float v = (c < 64) ? Wl2[k * 64 + c] : Wr2[k * 64 + (c - 64)];
        wt2h[j] = f2b(v);
    } else {
        int j = p - 98304;
        if (j < total4) {
            float4 v = ((const float4*)x)[j];
            ushort4 h;
            h.x = f2b(v.x); h.y = f2b(v.y); h.z = f2b(v.z); h.w = f2b(v.w);
            ((ushort4*)xh)[j] = h;
        }
    }
}

// ---------------- MFMA GEMM (single-term bf16), weights LDS-resident ----------------

template<int K, int HALF>
__global__ __launch_bounds__(256) void k_gemm_mfma(
        const ushort* __restrict__ a_hi, int AS,
        const ushort* __restrict__ wt_hi,
        ushort* __restrict__ out0, ushort* __restrict__ out1, int N, int nrt) {
    constexpr int LDK = K + 8;
    __shared__ ushort w_hi[128 * LDK];

    int tid = threadIdx.x;
    int cg  = blockIdx.y;
    const uint4* gh = (const uint4*)(wt_hi + (size_t)cg * 128 * K);
#pragma unroll
    for (int j = 0; j < (128 * K / 8) / 256; j++) {
        int idx = j * 256 + tid;
        int col = idx / (K / 8), k8 = idx % (K / 8);
        *(uint4*)&w_hi[col * LDK + k8 * 8] = gh[idx];
    }
    __syncthreads();

    int wid  = tid >> 6, lane = tid & 63;
    int wrg  = wid & 1;          // row group (32 rows)
    int wcg  = wid >> 1;         // col group (64 cols)
    int r16  = lane & 15, kq = lane >> 4;

    int gcol0 = cg * 128 + wcg * 64;     // wave's 64 cols lie fully in one half
    ushort* dst = (gcol0 < HALF) ? out0 : out1;
    int dcol0 = (gcol0 < HALF) ? gcol0 : gcol0 - HALF;

    for (int rt = blockIdx.x; rt < nrt; rt += gridDim.x) {
        int row0 = rt * 64 + wrg * 32;
        f32x4 acc[2][4];
#pragma unroll
        for (int rh = 0; rh < 2; rh++)
#pragma unroll
            for (int t = 0; t < 4; t++) acc[rh][t] = (f32x4){0.f, 0.f, 0.f, 0.f};

#pragma unroll
        for (int kk = 0; kk < K / 32; kk++) {
            int ko = kk * 32 + kq * 8;
            short8b ah[2];
#pragma unroll
            for (int rh = 0; rh < 2; rh++) {
                int arow = min(row0 + rh * 16 + r16, N - 1);
                ah[rh] = *(const short8b*)(a_hi + (size_t)arow * AS + ko);
            }
#pragma unroll
            for (int t = 0; t < 4; t++) {
                int wcol = wcg * 64 + t * 16 + r16;
                short8b bh = *(const short8b*)&w_hi[wcol * LDK + ko];
#pragma unroll
                for (int rh = 0; rh < 2; rh++)
                    acc[rh][t] = __builtin_amdgcn_mfma_f32_16x16x32_bf16(ah[rh], bh, acc[rh][t], 0, 0, 0);
            }
        }
#pragma unroll
        for (int rh = 0; rh < 2; rh++)
#pragma unroll
            for (int t = 0; t < 4; t++)
#pragma unroll
                for (int r = 0; r < 4; r++) {
                    int row = row0 + rh * 16 + kq * 4 + r;
                    if (row < N)
                        dst[(size_t)row * HALF + dcol0 + t * 16 + r16] = f2b(acc[rh][t][r]);
                }
    }
}

// ---------------- Layer 1 fused: one wave/node, 4 edges/iter (2 groups x unroll 2) ----------
// Two independent gathers in flight per lane; unrolled main body needs no idx masking.
// No max-subtraction (scores O(1) by construction). lrelu(z) = 0.6z + 0.4|z| (exact).

__global__ __launch_bounds__(256) void k_fused1(const int* __restrict__ srcs, int N,
                                                const int* __restrict__ offsets,
                                                const ushort* __restrict__ xl,
                                                const ushort* __restrict__ xr,
                                                const float* __restrict__ att,
                                                const float* __restrict__ b1,
                                                ushort* __restrict__ h1) {
    int wid  = (blockIdx.x * blockDim.x + threadIdx.x) >> 6;
    int lane = threadIdx.x & 63;
    if (wid >= N) return;
    int start = offsets[wid], end = offsets[wid + 1];
    int g = lane >> 5, l5 = lane & 31;
    int c0 = l5 * 8;

    floatx2 xr2[4], a06[4], a04[4], acc2[4];
    {
        uint4 xraw = *(const uint4*)(xr + (size_t)wid * 256 + c0);
        xr2[0] = (floatx2){b2f_lo(xraw.x), b2f_hi(xraw.x)};
        xr2[1] = (floatx2){b2f_lo(xraw.y), b2f_hi(xraw.y)};
        xr2[2] = (floatx2){b2f_lo(xraw.z), b2f_hi(xraw.z)};
        xr2[3] = (floatx2){b2f_lo(xraw.w), b2f_hi(xraw.w)};
    }
    const floatx2* atp = (const floatx2*)(att + c0);
#pragma unroll
    for (int i = 0; i < 4; i++) {
        floatx2 a = atp[i];
        a06[i] = a * 0.6f;
        a04[i] = a * 0.4f;
        acc2[i] = (floatx2){0.f, 0.f};
    }

    float ssum = 0.f;
    const ushort* xlp = xl + c0;
    for (int p0 = start; p0 < end; p0 += 64) {
        int cnt = end - p0; if (cnt > 64) cnt = 64;
        int sidx = (lane < cnt) ? srcs[p0 + lane] : 0;   // coalesced batch prefetch
        int j = 0;
        for (; j + 4 <= cnt; j += 4) {                   // main: 4 edges, no masking
            int s0 = __shfl(sidx, j + g);
            int s1 = __shfl(sidx, j + 2 + g);
            uint4 raw0 = *(const uint4*)(xlp + (size_t)s0 * 256);
            uint4 raw1 = *(const uint4*)(xlp + (size_t)s1 * 256);
            floatx2 v0[4], v1[4];
            v0[0] = (floatx2){b2f_lo(raw0.x), b2f_hi(raw0.x)};
            v0[1] = (floatx2){b2f_lo(raw0.y), b2f_hi(raw0.y)};
            v0[2] = (floatx2){b2f_lo(raw0.z), b2f_hi(raw0.z)};
            v0[3] = (floatx2){b2f_lo(raw0.w), b2f_hi(raw0.w)};
            v1[0] = (floatx2){b2f_lo(raw1.x), b2f_hi(raw1.x)};
            v1[1] = (floatx2){b2f_lo(raw1.y), b2f_hi(raw1.y)};
            v1[2] = (floatx2){b2f_lo(raw1.z), b2f_hi(raw1.z)};
            v1[3] = (floatx2){b2f_lo(raw1.w), b2f_hi(raw1.w)};
            floatx2 e20 = (floatx2){0.f, 0.f}, e21 = (floatx2){0.f, 0.f};
#pragma unroll
            for (int i = 0; i < 4; i++) {
                floatx2 z0 = v0[i] + xr2[i];
                floatx2 z1 = v1[i] + xr2[i];
                e20 += z0 * a06[i];
                e21 += z1 * a06[i];
                e20 += __builtin_elementwise_abs(z0) * a04[i];
                e21 += __builtin_elementwise_abs(z1) * a04[i];
            }
            float e0 = e20.x + e20.y;
            float e1 = e21.x + e21.y;
            e0 += __shfl_xor(e0, 1);
            e1 += __shfl_xor(e1, 1);
            e0 += __shfl_xor(e0, 2);
            e1 += __shfl_xor(e1, 2);
            float w0 = __expf(e0);
            float w1 = __expf(e1);
            ssum += w0 + w1;
            floatx2 w20 = (floatx2){w0, w0};
            floatx2 w21 = (floatx2){w1, w1};
#pragma unroll
            for (int i = 0; i < 4; i++) {
                acc2[i] += v0[i] * w20;
                acc2[i] += v1[i] * w21;
            }
        }
        for (; j < cnt; j += 2) {                        // tail: masked
            int idx = j + g;
            int s = __shfl(sidx, idx & 63);
            uint4 raw = *(const uint4*)(xlp + (size_t)s * 256);
            floatx2 v[4];
            v[0] = (floatx2){b2f_lo(raw.x), b2f_hi(raw.x)};
            v[1] = (floatx2){b2f_lo(raw.y), b2f_hi(raw.y)};
            v[2] = (floatx2){b2f_lo(raw.z), b2f_hi(raw.z)};
            v[3] = (floatx2){b2f_lo(raw.w), b2f_hi(raw.w)};
            floatx2 e2 = (floatx2){0.f, 0.f};
#pragma unroll
            for (int i = 0; i < 4; i++) {
                floatx2 z = v[i] + xr2[i];
                e2 += z * a06[i];
                e2 += __builtin_elementwise_abs(z) * a04[i];
            }
            float e = e2.x + e2.y;
            e += __shfl_xor(e, 1);
            e += __shfl_xor(e, 2);
            float w = (idx < cnt) ? __expf(e) : 0.f;
            ssum += w;
            floatx2 w2 = (floatx2){w, w};
#pragma unroll
            for (int i = 0; i < 4; i++) acc2[i] += v[i] * w2;
        }
    }
    // merge the two edge-groups
    ssum += __shfl_xor(ssum, 32);
#pragma unroll
    for (int i = 0; i < 4; i++) {
        acc2[i].x += __shfl_xor(acc2[i].x, 32);
        acc2[i].y += __shfl_xor(acc2[i].y, 32);
    }

    if (g == 0) {
        const floatx2* bvp = (const floatx2*)(b1 + c0);
        float inv = 1.f / ssum;
        ushort oh[8];
#pragma unroll
        for (int i = 0; i < 4; i++) {
            floatx2 bv = bvp[i];
            oh[2*i]   = f2b(elu1(acc2[i].x * inv + bv.x));
            oh[2*i+1] = f2b(elu1(acc2[i].y * inv + bv.y));
        }
        *(uint4*)(h1 + (size_t)wid * 256 + c0) = *(uint4*)oh;
    }
}

// ---------------- Layer 2 fused (final output), one wave/node, 8 edges/iter ----------------

__global__ __launch_bounds__(256) void k_fused2(const int* __restrict__ srcs, int N,
                                                const int* __restrict__ offsets,
                                                const ushort* __restrict__ xl,
                                                const ushort* __restrict__ xr,
                                                const float* __restrict__ att,
                                                const float* __restrict__ b2,
                                                float* __restrict__ out) {
    int wid  = (blockIdx.x * blockDim.x + threadIdx.x) >> 6;
    int lane = threadIdx.x & 63;
    if (wid >= N) return;
    int start = offsets[wid], end = offsets[wid + 1];
    int g = lane >> 4, l4 = lane & 15;
    int c0 = l4 * 4;

    floatx2 xr2[2], a06[2], a04[2], acc2[2];
    {
        uint2 xraw = *(const uint2*)(xr + (size_t)wid * 64 + c0);
        xr2[0] = (floatx2){b2f_lo(xraw.x), b2f_hi(xraw.x)};
        xr2[1] = (floatx2){b2f_lo(xraw.y), b2f_hi(xraw.y)};
    }
    const floatx2* atp = (const floatx2*)(att + c0);
#pragma unroll
    for (int i = 0; i < 2; i++) {
        floatx2 a = atp[i];
        a06[i] = a * 0.6f;
        a04[i] = a * 0.4f;
        acc2[i] = (floatx2){0.f, 0.f};
    }

    float ssum = 0.f;
    const ushort* xlp = xl + c0;
    for (int p0 = start; p0 < end; p0 += 64) {
        int cnt = end - p0; if (cnt > 64) cnt = 64;
        int sidx = (lane < cnt) ? srcs[p0 + lane] : 0;
        int j = 0;
        for (; j + 8 <= cnt; j += 8) {                   // main: 8 edges, no masking
            int s0 = __shfl(sidx, j + g);
            int s1 = __shfl(sidx, j + 4 + g);
            uint2 raw0 = *(const uint2*)(xlp + (size_t)s0 * 64);
            uint2 raw1 = *(const uint2*)(xlp + (size_t)s1 * 64);
            floatx2 v0[2], v1[2];
            v0[0] = (floatx2){b2f_lo(raw0.x), b2f_hi(raw0.x)};
            v0[1] = (floatx2){b2f_lo(raw0.y), b2f_hi(raw0.y)};
            v1[0] = (floatx2){b2f_lo(raw1.x), b2f_hi(raw1.x)};
            v1[1] = (floatx2){b2f_lo(raw1.y), b2f_hi(raw1.y)};
            floatx2 e20 = (floatx2){0.f, 0.f}, e21 = (floatx2){0.f, 0.f};
#pragma unroll
            for (int i = 0; i < 2; i++) {
                floatx2 z0 = v0[i] + xr2[i];
                floatx2 z1 = v1[i] + xr2[i];
                e20 += z0 * a06[i];
                e21 += z1 * a06[i];
                e20 += __builtin_elementwise_abs(z0) * a04[i];
                e21 += __builtin_elementwise_abs(z1) * a04[i];
            }
            float e0 = e20.x + e20.y;
            float e1 = e21.x + e21.y;
            e0 += __shfl_xor(e0, 1);
            e1 += __shfl_xor(e1, 1);
            e0 += __shfl_xor(e0, 2);
            e1 += __shfl_xor(e1, 2);
            e0 += __shfl_xor(e0, 4);
            e1 += __shfl_xor(e1, 4);
            e0 += __shfl_xor(e0, 8);
            e1 += __shfl_xor(e1, 8);
            float w0 = __expf(e0);
            float w1 = __expf(e1);
            ssum += w0 + w1;
            floatx2 w20 = (floatx2){w0, w0};
            floatx2 w21 = (floatx2){w1, w1};
#pragma unroll
            for (int i = 0; i < 2; i++) {
                acc2[i] += v0[i] * w20;
                acc2[i] += v1[i] * w21;
            }
        }
        for (; j < cnt; j += 4) {                        // tail: masked
            int idx = j + g;
            int s = __shfl(sidx, idx & 63);
            uint2 raw = *(const uint2*)(xlp + (size_t)s * 64);
            floatx2 v[2];
            v[0] = (floatx2){b2f_lo(raw.x), b2f_hi(raw.x)};
            v[1] = (floatx2){b2f_lo(raw.y), b2f_hi(raw.y)};
            floatx2 e2 = (floatx2){0.f, 0.f};
#pragma unroll
            for (int i = 0; i < 2; i++) {
                floatx2 z = v[i] + xr2[i];
                e2 += z * a06[i];
                e2 += __builtin_elementwise_abs(z) * a04[i];
            }
            float e = e2.x + e2.y;
            e += __shfl_xor(e, 1);
            e += __shfl_xor(e, 2);
            e += __shfl_xor(e, 4);
            e += __shfl_xor(e, 8);
            float w = (idx < cnt) ? __expf(e) : 0.f;
            ssum += w;
            floatx2 w2 = (floatx2){w, w};
#pragma unroll
            for (int i = 0; i < 2; i++) acc2[i] += v[i] * w2;
        }
    }
    // merge the four edge-groups
    ssum += __shfl_xor(ssum, 16);
    ssum += __shfl_xor(ssum, 32);
#pragma unroll
    for (int i = 0; i < 2; i++) {
        acc2[i].x += __shfl_xor(acc2[i].x, 16);
        acc2[i].x += __shfl_xor(acc2[i].x, 32);
        acc2[i].y += __shfl_xor(acc2[i].y, 16);
        acc2[i].y += __shfl_xor(acc2[i].y, 32);
    }
    if (g == 0) {
        float4 bv = *(const float4*)(b2 + c0);
        float inv = 1.f / ssum;
        float4 o;
        o.x = acc2[0].x * inv + bv.x;
        o.y = acc2[0].y * inv + bv.y;
        o.z = acc2[1].x * inv + bv.z;
        o.w = acc2[1].y * inv + bv.w;
        *(float4*)(out + (size_t)wid * 64 + c0) = o;
    }
}

// ---------------- launch ----------------

extern "C" void kernel_launch(void* const* d_in, const int* in_sizes, int n_in,
                              void* d_out, int out_size, void* d_ws, size_t ws_size,
                              hipStream_t stream) {
    const float* x    = (const float*)d_in[0];
    const int*   ei   = (const int*)d_in[1];
    // d_in[2] edge_type unused by forward
    const float* Wl1  = (const float*)d_in[3];
    const float* Wr1  = (const float*)d_in[4];
    const float* att1 = (const float*)d_in[5];
    const float* b1   = (const float*)d_in[6];
    const float* Wl2  = (const float*)d_in[7];
    const float* Wr2  = (const float*)d_in[8];
    const float* att2 = (const float*)d_in[9];
    const float* b2   = (const float*)d_in[10];
    float* out = (float*)d_out;

    const int N  = in_sizes[0] / 128;  // 50000
    const int E  = in_sizes[1] / 2;    // 800000
    const int Et = E + N;              // with self loops
    const int nrt = (N + 63) / 64;     // 64-row tiles
    const int nsb = (N + SCAN_BPB - 1) / SCAN_BPB;  // scan blocks (49) — must be <= 256

    // ---- workspace layout ----
    char* ws = (char*)d_ws;
    size_t off = 0;
    auto alloc = [&](size_t bytes) { size_t o = off; off += (bytes + 255) & ~(size_t)255; return o; };
    size_t o_xl1     = alloc((size_t)N * 256 * 2);   // bf16
    size_t o_xr1     = alloc((size_t)N * 256 * 2);   // bf16
    size_t o_h1      = alloc((size_t)N * 256 * 2);   // bf16
    size_t o_offsets = alloc((size_t)(N + 1) * 4);
    size_t o_deg     = alloc((size_t)N * 4);
    size_t o_cursor  = alloc((size_t)N * 4);
    size_t o_srcs    = alloc((size_t)Et * 4);
    size_t o_bsum    = alloc((size_t)256 * 4);
    size_t o_wt1h    = alloc((size_t)512 * 128 * 2);
    size_t o_wt2h    = alloc((size_t)128 * 256 * 2);
    size_t o_xh      = alloc((size_t)N * 128 * 2);
    size_t o_xl2     = alloc((size_t)N * 64 * 2);    // bf16
    size_t o_xr2     = alloc((size_t)N * 64 * 2);    // bf16
    (void)ws_size;

    ushort* xl1     = (ushort*)(ws + o_xl1);
    ushort* xr1     = (ushort*)(ws + o_xr1);
    ushort* h1      = (ushort*)(ws + o_h1);
    int*    offsets = (int*)(ws + o_offsets);
    int*    deg     = (int*)(ws + o_deg);
    int*    cursor  = (int*)(ws + o_cursor);
    int*    srcs    = (int*)(ws + o_srcs);
    int*    bsum    = (int*)(ws + o_bsum);
    ushort* wt1h    = (ushort*)(ws + o_wt1h);
    ushort* wt2h    = (ushort*)(ws + o_wt2h);
    ushort* xh      = (ushort*)(ws + o_xh);
    ushort* xl2     = (ushort*)(ws + o_xl2);
    ushort* xr2     = (ushort*)(ws + o_xr2);

    // ---- CSR build + fused prep ----
    hipMemsetAsync(deg, 0, (size_t)N * 4, stream);
    int tb = 256;
    int total4 = N * 128 / 4;
    int prep_items = Et + 98304 + total4;
    k_prep<<<(prep_items + tb - 1) / tb, tb, 0, stream>>>(ei, E, Et, deg,
                                                          Wl1, Wr1, wt1h,
                                                          Wl2, Wr2, wt2h,
                                                          x, xh, total4);
    k_scan1<<<nsb, 256, 0, stream>>>(deg, N, bsum);
    k_scan3<<<nsb, 256, 0, stream>>>(deg, N, bsum, nsb, offsets, cursor);
    k_scatter<<<(Et + tb - 1) / tb, tb, 0, stream>>>(ei, E, Et, cursor, srcs);

    // ---- layer 1: A = xh (stride 128), 4 col-groups of 128 over 512 cols ----
    k_gemm_mfma<128, 256><<<dim3(256, 4), 256, 0, stream>>>(xh, 128, wt1h, xl1, xr1, N, nrt);
    k_fused1<<<(N + 3) / 4, 256, 0, stream>>>(srcs, N, offsets, xl1, xr1, att1, b1, h1);

    // ---- layer 2: A = h1 bf16 (stride 256), 1 col-group of 128 ----
    k_gemm_mfma<256, 64><<<dim3(392, 1), 256, 0, stream>>>(h1, 256, wt2h, xl2, xr2, N, nrt);
    k_fused2<<<(N + 3) / 4, 256, 0, stream>>>(srcs, N, offsets, xl2, xr2, att2, b2, out);
}